// Round 5
// baseline (4413.535 us; speedup 1.0000x reference)
//
#include <hip/hip_runtime.h>
#include <hip/hip_bf16.h>

typedef short s16x8 __attribute__((ext_vector_type(8)));
typedef int   i32x4 __attribute__((ext_vector_type(4)));
typedef float f32x4 __attribute__((ext_vector_type(4)));
typedef float f32x2 __attribute__((ext_vector_type(2)));

#define T_STEPS 1024
#define BATCH   128
#define DIN     256
#define DH      256
#define NWG     64     // 8 batch-groups (x16 rows) x 8 column-slices (x32 h-cols)
#define NTHREADS 256

static __device__ __forceinline__ short f2bf(float f) {
  return __builtin_bit_cast(short, (__bf16)f);   // RNE hardware convert
}
static __device__ __forceinline__ float sigf(float x){ return 1.f/(1.f+__expf(-x)); }
static __device__ __forceinline__ float tanhfast(float x){ return 1.f - 2.f/(1.f+__expf(2.f*x)); }

// ---- proven MALL-coherent primitives (round 3): sc0 sc1 = bypass L1+L2 ----
static __device__ __forceinline__ i32x4 ld16_cc(const void* p){
  i32x4 r; asm volatile("global_load_dwordx4 %0, %1, off sc0 sc1" : "=v"(r) : "v"(p) : "memory"); return r;
}
static __device__ __forceinline__ unsigned ld4_cc(const void* p){
  unsigned r; asm volatile("global_load_dword %0, %1, off sc0 sc1\ns_waitcnt vmcnt(0)" : "=v"(r) : "v"(p) : "memory"); return r;
}
static __device__ __forceinline__ void st4_cc(void* p, unsigned v){
  asm volatile("global_store_dword %0, %1, off sc0 sc1" :: "v"(p), "v"(v) : "memory");
}

static __device__ __forceinline__ s16x8 cvt8(f32x4 a, f32x4 b){
  s16x8 r;
  r[0]=f2bf(a[0]); r[1]=f2bf(a[1]); r[2]=f2bf(a[2]); r[3]=f2bf(a[3]);
  r[4]=f2bf(b[0]); r[5]=f2bf(b[1]); r[6]=f2bf(b[2]); r[7]=f2bf(b[3]);
  return r;
}

__global__ __launch_bounds__(NTHREADS, 1)
void lstm_rc(const float* __restrict__ X,
             const float* __restrict__ Wf, const float* __restrict__ bfv,
             const float* __restrict__ Wi, const float* __restrict__ biv,
             const float* __restrict__ Wg, const float* __restrict__ bgv,
             const float* __restrict__ Wo, const float* __restrict__ bov,
             float* __restrict__ out,
             unsigned short* __restrict__ hbuf,   // [2][128][256] bf16 bits
             unsigned int* __restrict__ flags,    // [8 groups][32 dwords] (1 line/group)
             int needEnd)
{
  const int bid = blockIdx.x;
  const int r   = bid & 7;        // batch group (rows r*16 .. r*16+15)
  const int csl = bid >> 3;       // column slice: h-cols [32*csl, 32*csl+32)
  const int tid = threadIdx.x;
  const int lane = tid & 63, wv = tid >> 6;
  const int grp = lane >> 4, l15 = lane & 15;
  const int r0 = r * 16;

  __shared__ short bfx[64 * 64 * 8];   // x-part B frags: [(wv*2+n2)*8+kk][lane][8], 64 KB
  __shared__ float elds[4 * 16 * 36];  // per-wave epilogue bounce, 9 KB

  // ---- weights: x-part (k<256) -> LDS frags, h-part (k>=256) -> regs ----
  s16x8 bh[2][8];
  {
    const float* Wm[4] = {Wf, Wi, Wg, Wo};
    const int gate = l15 >> 2, jj = l15 & 3;
    const float* Wsrc = Wm[gate];
#pragma unroll
    for (int n2 = 0; n2 < 2; ++n2) {
      const int hc = csl * 32 + (wv * 2 + n2) * 4 + jj;
#pragma unroll
      for (int kk = 0; kk < 16; ++kk) {
        const float* p = Wsrc + (size_t)(kk * 32 + grp * 8) * DH + hc;
        s16x8 f;
#pragma unroll
        for (int s = 0; s < 8; ++s) f[s] = f2bf(p[(size_t)s * DH]);
        if (kk < 8) *(s16x8*)&bfx[(((wv * 2 + n2) * 8 + kk) * 64 + lane) * 8] = f;
        else        bh[n2][kk - 8] = f;
      }
    }
  }

  // this lane's 2 cells: row r0+l15, cols colg, colg+1
  const int colg = csl * 32 + wv * 8 + 2 * grp;
  float bia[4][2];
  {
    const float* Bv[4] = {bfv, biv, bgv, bov};
#pragma unroll
    for (int g = 0; g < 4; ++g) { bia[g][0] = Bv[g][colg]; bia[g][1] = Bv[g][colg + 1]; }
  }
  __syncthreads();                 // bfx ready (read-only hereafter)

  // ---- preloop: x(0) -> regs (plain, compiler-tracked), accx(0) ----
  f32x4 xr[16];
  {
    const float* xs0 = X + (size_t)(r0 + l15) * DIN + grp * 8;
#pragma unroll
    for (int kk = 0; kk < 8; ++kk) {
      xr[2 * kk]     = *(const f32x4*)(xs0 + kk * 32);
      xr[2 * kk + 1] = *(const f32x4*)(xs0 + kk * 32 + 4);
    }
  }
  f32x4 accx0 = {0.f,0.f,0.f,0.f}, accx1 = {0.f,0.f,0.f,0.f};
#pragma unroll
  for (int kk = 0; kk < 8; ++kk) {
    s16x8 fa = cvt8(xr[2 * kk], xr[2 * kk + 1]);
    s16x8 b0 = *(const s16x8*)&bfx[(((wv * 2 + 0) * 8 + kk) * 64 + lane) * 8];
    s16x8 b1 = *(const s16x8*)&bfx[(((wv * 2 + 1) * 8 + kk) * 64 + lane) * 8];
    accx0 = __builtin_amdgcn_mfma_f32_16x16x32_bf16(fa, b0, accx0, 0, 0, 0);
    accx1 = __builtin_amdgcn_mfma_f32_16x16x32_bf16(fa, b1, accx1, 0, 0, 0);
  }

  unsigned* myflag = flags + (r * 32 + csl);
  const unsigned* pollp = flags + (r * 32 + (lane & 7));
  float* eldsw = &elds[wv * 16 * 36];
  float cs0 = 0.f, cs1 = 0.f, h0s = 0.f, h1s = 0.f;

  for (int t = 0; t < T_STEPS; ++t) {
    // ---- poll: all lanes watch the group's 8 WG-flags (one cacheline) ----
    while (1) {
      unsigned v = ld4_cc(pollp);
      if (__all((int)(v >= (unsigned)t))) break;
    }
    __builtin_amdgcn_sched_barrier(0);

    // ---- h(t) loads; poll drained vmcnt -> vmcnt(0) waits exactly these ----
    const unsigned short* hr = hbuf + (size_t)(t & 1) * (BATCH * DH)
                             + (size_t)(r0 + l15) * DH + grp * 8;
    i32x4 hraw[8];
#pragma unroll
    for (int q = 0; q < 8; ++q) hraw[q] = ld16_cc(hr + q * 32);
    asm volatile("s_waitcnt vmcnt(0)" ::: "memory");
    __builtin_amdgcn_sched_barrier(0);

    // ---- h-part MFMAs on top of precomputed x-part ----
    f32x4 acc0 = accx0, acc1 = accx1;
#pragma unroll
    for (int q = 0; q < 8; ++q) {
      s16x8 ah = __builtin_bit_cast(s16x8, hraw[q]);
      acc0 = __builtin_amdgcn_mfma_f32_16x16x32_bf16(ah, bh[0][q], acc0, 0, 0, 0);
      acc1 = __builtin_amdgcn_mfma_f32_16x16x32_bf16(ah, bh[1][q], acc1, 0, 0, 0);
    }

    // ---- per-wave transpose bounce (intra-wave only: no barrier) ----
#pragma unroll
    for (int rr = 0; rr < 4; ++rr) {
      eldsw[(grp * 4 + rr) * 36 + l15]      = acc0[rr];
      eldsw[(grp * 4 + rr) * 36 + 16 + l15] = acc1[rr];
    }
    asm volatile("s_waitcnt lgkmcnt(0)" ::: "memory");
    __builtin_amdgcn_sched_barrier(0);
    float z0[4], z1[4];
    const int hc0 = 2 * grp, hc1 = 2 * grp + 1;
#pragma unroll
    for (int g = 0; g < 4; ++g) {
      z0[g] = eldsw[l15 * 36 + ((hc0 >> 2) << 4) + 4 * g + (hc0 & 3)];
      z1[g] = eldsw[l15 * 36 + ((hc1 >> 2) << 4) + 4 * g + (hc1 & 3)];
    }

    // ---- cell update (2 cells) ----
    {
      float zf = z0[0] + bia[0][0], zi = z0[1] + bia[1][0];
      float zg = z0[2] + bia[2][0], zo = z0[3] + bia[3][0];
      cs0 = sigf(zf) * cs0 + sigf(zi) * tanhfast(zg);
      h0s = sigf(zo) * tanhfast(cs0);
    }
    {
      float zf = z1[0] + bia[0][1], zi = z1[1] + bia[1][1];
      float zg = z1[2] + bia[2][1], zo = z1[3] + bia[3][1];
      cs1 = sigf(zf) * cs1 + sigf(zi) * tanhfast(zg);
      h1s = sigf(zo) * tanhfast(cs1);
    }

    // ---- h(t+1) store (MALL), drain, barrier, publish ----
    const int row = r0 + l15;
    {
      unsigned hpk = (unsigned)(unsigned short)f2bf(h0s)
                   | ((unsigned)(unsigned short)f2bf(h1s) << 16);
      st4_cc(hbuf + (size_t)((t + 1) & 1) * (BATCH * DH)
             + (size_t)row * DH + colg, hpk);
    }
    asm volatile("s_waitcnt vmcnt(0)" ::: "memory");   // own h-store at MALL
    __syncthreads();                                   // all waves drained
    if (tid == 0) st4_cc(myflag, (unsigned)(t + 1));

    // ---- shadow work: out store, x(t+1) load, x-part precompute ----
    {
      f32x2 ov; ov[0] = h0s; ov[1] = h1s;
      *(f32x2*)(out + ((size_t)t * BATCH + row) * DH + colg) = ov;
    }
    {
      const int tnx = (t + 1 < T_STEPS) ? t + 1 : T_STEPS - 1;
      const float* xs = X + ((size_t)tnx * BATCH + r0 + l15) * DIN + grp * 8;
#pragma unroll
      for (int kk = 0; kk < 8; ++kk) {
        xr[2 * kk]     = *(const f32x4*)(xs + kk * 32);
        xr[2 * kk + 1] = *(const f32x4*)(xs + kk * 32 + 4);
      }
    }
    accx0 = (f32x4){0.f,0.f,0.f,0.f}; accx1 = (f32x4){0.f,0.f,0.f,0.f};
#pragma unroll
    for (int kk = 0; kk < 8; ++kk) {
      s16x8 fa = cvt8(xr[2 * kk], xr[2 * kk + 1]);
      s16x8 b0 = *(const s16x8*)&bfx[(((wv * 2 + 0) * 8 + kk) * 64 + lane) * 8];
      s16x8 b1 = *(const s16x8*)&bfx[(((wv * 2 + 1) * 8 + kk) * 64 + lane) * 8];
      accx0 = __builtin_amdgcn_mfma_f32_16x16x32_bf16(fa, b0, accx0, 0, 0, 0);
      accx1 = __builtin_amdgcn_mfma_f32_16x16x32_bf16(fa, b1, accx1, 0, 0, 0);
    }
  }

  // ---- final hx, cx (fp32, from registers) ----
  if (needEnd) {
    // hbuf/flags alias the hx/cx tail of d_out: wait until every WG finished
    if (wv == 0) {
      const unsigned* fp = flags + ((lane >> 3) * 32 + (lane & 7));
      while (ld4_cc(fp) < (unsigned)T_STEPS) __builtin_amdgcn_s_sleep(1);
    }
    __syncthreads();
  }
  {
    const size_t base = (size_t)T_STEPS * BATCH * DH;
    const size_t idx  = (size_t)(r0 + l15) * DH + colg;
    out[base + idx]     = h0s;
    out[base + idx + 1] = h1s;
    out[base + BATCH * DH + idx]     = cs0;
    out[base + BATCH * DH + idx + 1] = cs1;
  }
}

extern "C" void kernel_launch(void* const* d_in, const int* in_sizes, int n_in,
                              void* d_out, int out_size, void* d_ws, size_t ws_size,
                              hipStream_t stream) {
  const float* X   = (const float*)d_in[0];
  const float* Wf  = (const float*)d_in[1];
  const float* bf_ = (const float*)d_in[2];
  const float* Wi  = (const float*)d_in[3];
  const float* bi_ = (const float*)d_in[4];
  const float* Wg  = (const float*)d_in[5];
  const float* bg_ = (const float*)d_in[6];
  const float* Wo  = (const float*)d_in[7];
  const float* bo_ = (const float*)d_in[8];
  float* out = (float*)d_out;

  const size_t hbytes = (size_t)2 * BATCH * DH * 2;   // 131072
  const size_t fbytes = 2048;
  unsigned short* hbuf;
  unsigned int*   flags;
  int needEnd;
  if (ws_size >= hbytes + fbytes) {
    hbuf  = (unsigned short*)d_ws;
    flags = (unsigned int*)((unsigned char*)d_ws + hbytes);
    needEnd = 0;
    hipMemsetAsync(d_ws, 0, hbytes + fbytes, stream);
  } else {
    unsigned char* tail = (unsigned char*)d_out + (size_t)T_STEPS * BATCH * DH * 4;
    hbuf  = (unsigned short*)tail;
    flags = (unsigned int*)(tail + hbytes);
    needEnd = 1;
    hipMemsetAsync(tail, 0, hbytes + fbytes, stream);
  }

  lstm_rc<<<NWG, NTHREADS, 0, stream>>>(X, Wf, bf_, Wi, bi_, Wg, bg_,
                                        Wo, bo_, out, hbuf, flags, needEnd);
}

// Round 6
// 4260.563 us; speedup vs baseline: 1.0359x; 1.0359x over previous
//
#include <hip/hip_runtime.h>
#include <hip/hip_bf16.h>

typedef short s16x8 __attribute__((ext_vector_type(8)));
typedef int   i32x4 __attribute__((ext_vector_type(4)));
typedef float f32x4 __attribute__((ext_vector_type(4)));
typedef float f32x2 __attribute__((ext_vector_type(2)));

#define T_STEPS 1024
#define BATCH   128
#define DIN     256
#define DH      256
#define NWG     32     // 4 batch-groups (x32 rows, 2 phases x16) x 8 col-slices (x32 h-cols)
#define NTHREADS 256

static __device__ __forceinline__ short f2bf(float f){ return __builtin_bit_cast(short,(__bf16)f); }
static __device__ __forceinline__ float sigf(float x){ return 1.f/(1.f+__expf(-x)); }
static __device__ __forceinline__ float tanhfast(float x){ return 1.f-2.f/(1.f+__expf(2.f*x)); }

// ---- issue-only asm VMEM (proven sc0 sc1 = MALL-coherent); explicit waits ----
static __device__ __forceinline__ i32x4 ld16_cc_i(const void* p){ i32x4 r; asm volatile("global_load_dwordx4 %0, %1, off sc0 sc1" : "=v"(r) : "v"(p) : "memory"); return r; }
static __device__ __forceinline__ i32x4 ld16_pl_i(const void* p){ i32x4 r; asm volatile("global_load_dwordx4 %0, %1, off" : "=v"(r) : "v"(p) : "memory"); return r; }
static __device__ __forceinline__ unsigned ld4_cc_i(const void* p){ unsigned r; asm volatile("global_load_dword %0, %1, off sc0 sc1" : "=v"(r) : "v"(p) : "memory"); return r; }
static __device__ __forceinline__ unsigned ld4_cc_w(const void* p){ unsigned r; asm volatile("global_load_dword %0, %1, off sc0 sc1\ns_waitcnt vmcnt(0)" : "=v"(r) : "v"(p) : "memory"); return r; }
static __device__ __forceinline__ void st4_cc_i(void* p, unsigned v){ asm volatile("global_store_dword %0, %1, off sc0 sc1" :: "v"(p), "v"(v) : "memory"); }
static __device__ __forceinline__ void st8_pl_i(void* p, f32x2 v){ asm volatile("global_store_dwordx2 %0, %1, off" :: "v"(p), "v"(v) : "memory"); }
#define VMW(n)  asm volatile("s_waitcnt vmcnt(" #n ")" ::: "memory")
#define LGKM0   asm volatile("s_waitcnt lgkmcnt(0)" ::: "memory")
#define SCHED0  __builtin_amdgcn_sched_barrier(0)
#define POLLWAIT(val, ptr, tgt) \
  while (!__all((int)((val) >= (unsigned)(tgt)))) { (val) = ld4_cc_w(ptr); }

static __device__ __forceinline__ void stageX(short* dst, int xseg, int xrow,
                                              f32x4 a, f32x4 b, f32x4 c, f32x4 d){
  s16x8 lo, hi;
  lo[0]=f2bf(a[0]); lo[1]=f2bf(a[1]); lo[2]=f2bf(a[2]); lo[3]=f2bf(a[3]);
  lo[4]=f2bf(b[0]); lo[5]=f2bf(b[1]); lo[6]=f2bf(b[2]); lo[7]=f2bf(b[3]);
  hi[0]=f2bf(c[0]); hi[1]=f2bf(c[1]); hi[2]=f2bf(c[2]); hi[3]=f2bf(c[3]);
  hi[4]=f2bf(d[0]); hi[5]=f2bf(d[1]); hi[6]=f2bf(d[2]); hi[7]=f2bf(d[3]);
  *(s16x8*)&dst[((2*xseg+0)*16 + xrow)*8] = lo;
  *(s16x8*)&dst[((2*xseg+1)*16 + xrow)*8] = hi;
}

__global__ __launch_bounds__(NTHREADS, 1)
void lstm_pipe(const float* __restrict__ X,
               const float* __restrict__ Wf, const float* __restrict__ bfv,
               const float* __restrict__ Wi, const float* __restrict__ biv,
               const float* __restrict__ Wg, const float* __restrict__ bgv,
               const float* __restrict__ Wo, const float* __restrict__ bov,
               float* __restrict__ out,
               unsigned short* __restrict__ hbuf,   // [2][128][256] bf16 bits
               unsigned int* __restrict__ flags,    // [4g][2p][8csl][4wv] = 256
               int needEnd)
{
  const int bid = blockIdx.x;
  const int g   = bid & 3;
  const int csl = bid >> 2;
  const int tid = threadIdx.x;
  const int lane = tid & 63, wv = tid >> 6;
  const int grp = lane >> 4, l15 = lane & 15;
  const int r0A = g * 32, r0B = g * 32 + 16;

  __shared__ short bfx[64 * 64 * 8];       // x-part B frags (both phases share), 64 KB
  __shared__ short axl[4 * 32 * 16 * 8];   // x A-frags: [phase*2+buf][frag][row][8], 32 KB
  __shared__ float elds[4 * 16 * 36];      // per-wave epilogue bounce, 9 KB

  // ---- weights: x-part (k<256) -> LDS frags, h-part (k>=256) -> regs ----
  s16x8 bh[2][8];
  {
    const float* Wm[4] = {Wf, Wi, Wg, Wo};
    const int gate = l15 >> 2, jj = l15 & 3;
    const float* Wsrc = Wm[gate];
#pragma unroll
    for (int n2 = 0; n2 < 2; ++n2) {
      const int hc = csl * 32 + (wv * 2 + n2) * 4 + jj;
#pragma unroll
      for (int kk = 0; kk < 16; ++kk) {
        const float* p = Wsrc + (size_t)(kk * 32 + grp * 8) * DH + hc;
        s16x8 f;
#pragma unroll
        for (int s = 0; s < 8; ++s) f[s] = f2bf(p[(size_t)s * DH]);
        if (kk < 8) *(s16x8*)&bfx[(((wv * 2 + n2) * 8 + kk) * 64 + lane) * 8] = f;
        else        bh[n2][kk - 8] = f;
      }
    }
  }

  const int colg = csl * 32 + wv * 8 + 2 * grp;   // lane's 2 h-cols (both phases)
  float bia[4][2];
  {
    const float* Bv[4] = {bfv, biv, bgv, bov};
#pragma unroll
    for (int q = 0; q < 4; ++q) { bia[q][0] = Bv[q][colg]; bia[q][1] = Bv[q][colg + 1]; }
  }
  __syncthreads();

  // ---- stage x(0) for both phases (compiler loads; barrier drains) ----
  const int xrow = tid & 15, xseg = tid >> 4;
  {
    const float* xsA = X + (size_t)(r0A + xrow) * DIN + xseg * 16;
    stageX(axl + 0 * (32 * 16 * 8), xseg, xrow,
           *(const f32x4*)xsA, *(const f32x4*)(xsA + 4),
           *(const f32x4*)(xsA + 8), *(const f32x4*)(xsA + 12));
    const float* xsB = X + (size_t)(r0B + xrow) * DIN + xseg * 16;
    stageX(axl + 2 * (32 * 16 * 8), xseg, xrow,
           *(const f32x4*)xsB, *(const f32x4*)(xsB + 4),
           *(const f32x4*)(xsB + 8), *(const f32x4*)(xsB + 12));
  }
  __syncthreads();   // vm+lgkm drained; asm op-queue starts clean

  const unsigned* pollA = flags + (g * 2 + 0) * 32 + (lane & 31);
  const unsigned* pollB = flags + (g * 2 + 1) * 32 + (lane & 31);
  unsigned* flagAw = flags + (g * 2 + 0) * 32 + csl * 4 + wv;
  unsigned* flagBw = flags + (g * 2 + 1) * 32 + csl * 4 + wv;
  float* eldsw = &elds[wv * 16 * 36];

  // prefetch x(1) for both phases + first pollA probe.  Q: [xA4, pA, xB4]
  f32x4 xra[4], xrb[4];
  {
    const float* xs = X + ((size_t)1 * BATCH + r0A + xrow) * DIN + xseg * 16;
    xra[0] = __builtin_bit_cast(f32x4, ld16_pl_i(xs));
    xra[1] = __builtin_bit_cast(f32x4, ld16_pl_i(xs + 4));
    xra[2] = __builtin_bit_cast(f32x4, ld16_pl_i(xs + 8));
    xra[3] = __builtin_bit_cast(f32x4, ld16_pl_i(xs + 12));
  }
  unsigned pav = ld4_cc_i(pollA), pbv;
  {
    const float* xs = X + ((size_t)1 * BATCH + r0B + xrow) * DIN + xseg * 16;
    xrb[0] = __builtin_bit_cast(f32x4, ld16_pl_i(xs));
    xrb[1] = __builtin_bit_cast(f32x4, ld16_pl_i(xs + 4));
    xrb[2] = __builtin_bit_cast(f32x4, ld16_pl_i(xs + 8));
    xrb[3] = __builtin_bit_cast(f32x4, ld16_pl_i(xs + 12));
  }

  float csA0 = 0.f, csA1 = 0.f, hA0v = 0.f, hA1v = 0.f;
  float csB0 = 0.f, csB1 = 0.f, hB0v = 0.f, hB1v = 0.f;

  for (int t = 0; t < T_STEPS; ++t) {
    const int pr = t & 1, pw = (t + 1) & 1;

    // ===== W0: Q=[outB,pubB,pA,xB4] -> drain thru pA; keep xB4 in flight =====
    VMW(4); SCHED0;
    POLLWAIT(pav, pollA, t);
    SCHED0;

    // issue pollB probe + h_A(t) loads
    pbv = ld4_cc_i(pollB);
    const unsigned short* hrA = hbuf + (size_t)pr * (BATCH * DH)
                              + (size_t)(r0A + l15) * DH + grp * 8;
    i32x4 ha[8];
#pragma unroll
    for (int q = 0; q < 8; ++q) ha[q] = ld16_cc_i(hrA + q * 32);

    // x-part A MFMAs from LDS (covers hA latency)
    f32x4 a0 = {0.f,0.f,0.f,0.f}, a1 = {0.f,0.f,0.f,0.f};
    {
      const short* ab = axl + (0 * 2 + pr) * (32 * 16 * 8);
#pragma unroll
      for (int kk = 0; kk < 8; ++kk) {
        s16x8 a  = *(const s16x8*)&ab[((kk * 4 + grp) * 16 + l15) * 8];
        s16x8 b0 = *(const s16x8*)&bfx[(((wv * 2 + 0) * 8 + kk) * 64 + lane) * 8];
        s16x8 b1 = *(const s16x8*)&bfx[(((wv * 2 + 1) * 8 + kk) * 64 + lane) * 8];
        a0 = __builtin_amdgcn_mfma_f32_16x16x32_bf16(a, b0, a0, 0, 0, 0);
        a1 = __builtin_amdgcn_mfma_f32_16x16x32_bf16(a, b1, a1, 0, 0, 0);
      }
    }

    // ===== alpha_A: drain all (hA + pB + leftovers) =====
    VMW(0); SCHED0;
    POLLWAIT(pbv, pollB, t);
    SCHED0;

    // issue h_B(t) loads (latency covered by A's back half)
    const unsigned short* hrB = hbuf + (size_t)pr * (BATCH * DH)
                              + (size_t)(r0B + l15) * DH + grp * 8;
    i32x4 hb[8];
#pragma unroll
    for (int q = 0; q < 8; ++q) hb[q] = ld16_cc_i(hrB + q * 32);

    // h-part A MFMAs
#pragma unroll
    for (int q = 0; q < 8; ++q) {
      s16x8 ah = __builtin_bit_cast(s16x8, ha[q]);
      a0 = __builtin_amdgcn_mfma_f32_16x16x32_bf16(ah, bh[0][q], a0, 0, 0, 0);
      a1 = __builtin_amdgcn_mfma_f32_16x16x32_bf16(ah, bh[1][q], a1, 0, 0, 0);
    }

    // epilogue A: per-wave bounce + cell update
#pragma unroll
    for (int rr = 0; rr < 4; ++rr) {
      eldsw[(grp * 4 + rr) * 36 + l15]      = a0[rr];
      eldsw[(grp * 4 + rr) * 36 + 16 + l15] = a1[rr];
    }
    LGKM0; SCHED0;
    {
      const int hc0 = 2 * grp, hc1 = 2 * grp + 1;
      float z0[4], z1[4];
#pragma unroll
      for (int q = 0; q < 4; ++q) {
        z0[q] = eldsw[l15 * 36 + ((hc0 >> 2) << 4) + 4 * q + (hc0 & 3)];
        z1[q] = eldsw[l15 * 36 + ((hc1 >> 2) << 4) + 4 * q + (hc1 & 3)];
      }
      float zf = z0[0] + bia[0][0], zi = z0[1] + bia[1][0];
      float zg = z0[2] + bia[2][0], zo = z0[3] + bia[3][0];
      csA0 = sigf(zf) * csA0 + sigf(zi) * tanhfast(zg);
      hA0v = sigf(zo) * tanhfast(csA0);
      zf = z1[0] + bia[0][1]; zi = z1[1] + bia[1][1];
      zg = z1[2] + bia[2][1]; zo = z1[3] + bia[3][1];
      csA1 = sigf(zf) * csA1 + sigf(zi) * tanhfast(zg);
      hA1v = sigf(zo) * tanhfast(csA1);
    }

    // h-store A (cc) + out-store A.   Q=[hB8,hstA,outA]
    {
      unsigned hpk = (unsigned)(unsigned short)f2bf(hA0v)
                   | ((unsigned)(unsigned short)f2bf(hA1v) << 16);
      st4_cc_i(hbuf + (size_t)pw * (BATCH * DH) + (size_t)(r0A + l15) * DH + colg, hpk);
      f32x2 ov; ov[0] = hA0v; ov[1] = hA1v;
      st8_pl_i(out + ((size_t)t * BATCH + (r0A + l15)) * DH + colg, ov);
    }

    // stage x_A(t+1) BEFORE publish (poll implies staged for all waves)
    stageX(axl + (0 * 2 + pw) * (32 * 16 * 8), xseg, xrow, xra[0], xra[1], xra[2], xra[3]);
    LGKM0;

    // ===== beta_A: drain hB8+hstA, keep outA in flight; publish A =====
    VMW(1); SCHED0;
    if (lane == 0) st4_cc_i(flagAw, (unsigned)(t + 1));

    // prefetch x_A(t+2).   Q=[outA,pubA,xA4]
    {
      const int tp = (t + 2 < T_STEPS) ? t + 2 : T_STEPS - 1;
      const float* xs = X + ((size_t)tp * BATCH + r0A + xrow) * DIN + xseg * 16;
      xra[0] = __builtin_bit_cast(f32x4, ld16_pl_i(xs));
      xra[1] = __builtin_bit_cast(f32x4, ld16_pl_i(xs + 4));
      xra[2] = __builtin_bit_cast(f32x4, ld16_pl_i(xs + 8));
      xra[3] = __builtin_bit_cast(f32x4, ld16_pl_i(xs + 12));
    }

    // x-part B MFMAs from LDS
    f32x4 b0 = {0.f,0.f,0.f,0.f}, b1 = {0.f,0.f,0.f,0.f};
    {
      const short* ab = axl + (1 * 2 + pr) * (32 * 16 * 8);
#pragma unroll
      for (int kk = 0; kk < 8; ++kk) {
        s16x8 a  = *(const s16x8*)&ab[((kk * 4 + grp) * 16 + l15) * 8];
        s16x8 bb0 = *(const s16x8*)&bfx[(((wv * 2 + 0) * 8 + kk) * 64 + lane) * 8];
        s16x8 bb1 = *(const s16x8*)&bfx[(((wv * 2 + 1) * 8 + kk) * 64 + lane) * 8];
        b0 = __builtin_amdgcn_mfma_f32_16x16x32_bf16(a, bb0, b0, 0, 0, 0);
        b1 = __builtin_amdgcn_mfma_f32_16x16x32_bf16(a, bb1, b1, 0, 0, 0);
      }
    }
    // h-part B MFMAs (hb drained at beta_A)
#pragma unroll
    for (int q = 0; q < 8; ++q) {
      s16x8 ah = __builtin_bit_cast(s16x8, hb[q]);
      b0 = __builtin_amdgcn_mfma_f32_16x16x32_bf16(ah, bh[0][q], b0, 0, 0, 0);
      b1 = __builtin_amdgcn_mfma_f32_16x16x32_bf16(ah, bh[1][q], b1, 0, 0, 0);
    }

    // epilogue B
#pragma unroll
    for (int rr = 0; rr < 4; ++rr) {
      eldsw[(grp * 4 + rr) * 36 + l15]      = b0[rr];
      eldsw[(grp * 4 + rr) * 36 + 16 + l15] = b1[rr];
    }
    LGKM0; SCHED0;
    {
      const int hc0 = 2 * grp, hc1 = 2 * grp + 1;
      float z0[4], z1[4];
#pragma unroll
      for (int q = 0; q < 4; ++q) {
        z0[q] = eldsw[l15 * 36 + ((hc0 >> 2) << 4) + 4 * q + (hc0 & 3)];
        z1[q] = eldsw[l15 * 36 + ((hc1 >> 2) << 4) + 4 * q + (hc1 & 3)];
      }
      float zf = z0[0] + bia[0][0], zi = z0[1] + bia[1][0];
      float zg = z0[2] + bia[2][0], zo = z0[3] + bia[3][0];
      csB0 = sigf(zf) * csB0 + sigf(zi) * tanhfast(zg);
      hB0v = sigf(zo) * tanhfast(csB0);
      zf = z1[0] + bia[0][1]; zi = z1[1] + bia[1][1];
      zg = z1[2] + bia[2][1]; zo = z1[3] + bia[3][1];
      csB1 = sigf(zf) * csB1 + sigf(zi) * tanhfast(zg);
      hB1v = sigf(zo) * tanhfast(csB1);
    }

    // h-store B + out-store B.  Q=[outA,pubA,xA4,hstB,outB]
    {
      unsigned hpk = (unsigned)(unsigned short)f2bf(hB0v)
                   | ((unsigned)(unsigned short)f2bf(hB1v) << 16);
      st4_cc_i(hbuf + (size_t)pw * (BATCH * DH) + (size_t)(r0B + l15) * DH + colg, hpk);
      f32x2 ov; ov[0] = hB0v; ov[1] = hB1v;
      st8_pl_i(out + ((size_t)t * BATCH + (r0B + l15)) * DH + colg, ov);
    }

    // stage x_B(t+1) BEFORE publish
    stageX(axl + (1 * 2 + pw) * (32 * 16 * 8), xseg, xrow, xrb[0], xrb[1], xrb[2], xrb[3]);
    LGKM0;

    // ===== beta_B: drain outA,pubA,xA4,hstB; keep outB; publish B =====
    VMW(1); SCHED0;
    if (lane == 0) st4_cc_i(flagBw, (unsigned)(t + 1));

    // next-iter pollA probe + x_B(t+2) prefetch.  Q=[outB,pubB,pA,xB4]
    pav = ld4_cc_i(pollA);
    {
      const int tp = (t + 2 < T_STEPS) ? t + 2 : T_STEPS - 1;
      const float* xs = X + ((size_t)tp * BATCH + r0B + xrow) * DIN + xseg * 16;
      xrb[0] = __builtin_bit_cast(f32x4, ld16_pl_i(xs));
      xrb[1] = __builtin_bit_cast(f32x4, ld16_pl_i(xs + 4));
      xrb[2] = __builtin_bit_cast(f32x4, ld16_pl_i(xs + 8));
      xrb[3] = __builtin_bit_cast(f32x4, ld16_pl_i(xs + 12));
    }
  }

  // ---- final hx, cx (fp32, from registers) ----
  if (needEnd) {
    // hbuf/flags alias the hx/cx tail of d_out: wait until every wave finished
    const unsigned* fp = flags + tid;     // 256 flags, 256 threads
    while (ld4_cc_w(fp) < (unsigned)T_STEPS) __builtin_amdgcn_s_sleep(1);
    __syncthreads();
  }
  {
    const size_t base = (size_t)T_STEPS * BATCH * DH;
    const size_t idxA = (size_t)(r0A + l15) * DH + colg;
    const size_t idxB = (size_t)(r0B + l15) * DH + colg;
    out[base + idxA]     = hA0v;
    out[base + idxA + 1] = hA1v;
    out[base + BATCH * DH + idxA]     = csA0;
    out[base + BATCH * DH + idxA + 1] = csA1;
    out[base + idxB]     = hB0v;
    out[base + idxB + 1] = hB1v;
    out[base + BATCH * DH + idxB]     = csB0;
    out[base + BATCH * DH + idxB + 1] = csB1;
  }
}

extern "C" void kernel_launch(void* const* d_in, const int* in_sizes, int n_in,
                              void* d_out, int out_size, void* d_ws, size_t ws_size,
                              hipStream_t stream) {
  const float* X   = (const float*)d_in[0];
  const float* Wf  = (const float*)d_in[1];
  const float* bf_ = (const float*)d_in[2];
  const float* Wi  = (const float*)d_in[3];
  const float* bi_ = (const float*)d_in[4];
  const float* Wg  = (const float*)d_in[5];
  const float* bg_ = (const float*)d_in[6];
  const float* Wo  = (const float*)d_in[7];
  const float* bo_ = (const float*)d_in[8];
  float* out = (float*)d_out;

  const size_t hbytes = (size_t)2 * BATCH * DH * 2;   // 131072
  const size_t fbytes = 2048;
  unsigned short* hbuf;
  unsigned int*   flags;
  int needEnd;
  if (ws_size >= hbytes + fbytes) {
    hbuf  = (unsigned short*)d_ws;
    flags = (unsigned int*)((unsigned char*)d_ws + hbytes);
    needEnd = 0;
    hipMemsetAsync(d_ws, 0, hbytes + fbytes, stream);
  } else {
    unsigned char* tail = (unsigned char*)d_out + (size_t)T_STEPS * BATCH * DH * 4;
    hbuf  = (unsigned short*)tail;
    flags = (unsigned int*)(tail + hbytes);
    needEnd = 1;
    hipMemsetAsync(tail, 0, hbytes + fbytes, stream);
  }

  lstm_pipe<<<NWG, NTHREADS, 0, stream>>>(X, Wf, bf_, Wi, bi_, Wg, bg_,
                                          Wo, bo_, out, hbuf, flags, needEnd);
}